// Round 7
// baseline (213.822 us; speedup 1.0000x reference)
//
#include <hip/hip_runtime.h>
#include <hip/hip_cooperative_groups.h>
#include <math.h>

namespace cg = cooperative_groups;

#define BB 4
#define CC 64
#define NN 16384   // 128*128
#define HEADS 8
#define INNER 512

// One cooperative kernel, grid 256 x 256 (1 block/CU guaranteed resident:
// 61KB LDS, 256 threads). Phases separated by grid.sync():
//   1) Gram G_b = X_b X_b^T  (256 blocks, 256 cols each, atomicAdd -> G)
//   2) attention per (b,h,dquad) (blocks 0..127) -> attn_out + atomicAdd M
//   3) out = M^T X + bp      (256 blocks, 4 column-slices each)
__global__ __launch_bounds__(256) void k_fused(
        const float* __restrict__ x,
        const float* __restrict__ Wq,
        const float* __restrict__ Wk,
        const float* __restrict__ Wv,
        const float* __restrict__ Wp,
        const float* __restrict__ bp,
        const float* __restrict__ rescale,
        float* __restrict__ attn_out,
        float* __restrict__ G,
        float* __restrict__ Mg,
        float* __restrict__ out) {
    __shared__ float Gs[64][68];   // ph1: x-tile [n][c]; ph2: G; ph3: x-tile
    __shared__ float Tq[64][68];   // ph2: Tq, then WveffT(rows0-15)+Wp(rows16-31)
    __shared__ float Ws[64][68];   // ph2: Wq then Wv; ph3: M
    __shared__ float WkQ[64][20];  // ph2: Wk quarter
    __shared__ float Atn[64][20];  // ph2: TkQ then attnT
    __shared__ float qn[64];
    __shared__ float kn[16];

    const int bid = blockIdx.x;
    const int t = threadIdx.x;
    cg::grid_group grid = cg::this_grid();

    // ================= phase 1: Gram (atomic accumulate) =================
    {
        const int b = bid >> 6, s = bid & 63;
        const int g = t >> 6, lane = t & 63;
        const int rg = lane >> 4;
        const int r0 = g * 16 + rg * 4;        // output row block (c-dim)
        const int c0 = (lane & 15) * 4;        // output col block (c-dim)
        float acc[4][4];
#pragma unroll
        for (int i = 0; i < 4; i++)
#pragma unroll
            for (int j = 0; j < 4; j++) acc[i][j] = 0.f;

        const float* xb = x + (size_t)b * CC * NN;
        const int nbase = s * 256;             // 256 cols per slice
        for (int tile = 0; tile < 4; ++tile) {
            const int n0 = nbase + tile * 64;
#pragma unroll
            for (int k = 0; k < 4; k++) {
                int f = k * 256 + t;
                int c = f >> 4, j4 = f & 15;
                const float4 v = *reinterpret_cast<const float4*>(xb + (size_t)c * NN + n0 + j4 * 4);
                Gs[j4 * 4 + 0][c] = v.x; Gs[j4 * 4 + 1][c] = v.y;
                Gs[j4 * 4 + 2][c] = v.z; Gs[j4 * 4 + 3][c] = v.w;
            }
            __syncthreads();
#pragma unroll 8
            for (int n = 0; n < 64; ++n) {
                const float4 a4 = *reinterpret_cast<const float4*>(&Gs[n][r0]);
                const float4 b4 = *reinterpret_cast<const float4*>(&Gs[n][c0]);
                acc[0][0] = fmaf(a4.x, b4.x, acc[0][0]); acc[0][1] = fmaf(a4.x, b4.y, acc[0][1]);
                acc[0][2] = fmaf(a4.x, b4.z, acc[0][2]); acc[0][3] = fmaf(a4.x, b4.w, acc[0][3]);
                acc[1][0] = fmaf(a4.y, b4.x, acc[1][0]); acc[1][1] = fmaf(a4.y, b4.y, acc[1][1]);
                acc[1][2] = fmaf(a4.y, b4.z, acc[1][2]); acc[1][3] = fmaf(a4.y, b4.w, acc[1][3]);
                acc[2][0] = fmaf(a4.z, b4.x, acc[2][0]); acc[2][1] = fmaf(a4.z, b4.y, acc[2][1]);
                acc[2][2] = fmaf(a4.z, b4.z, acc[2][2]); acc[2][3] = fmaf(a4.z, b4.w, acc[2][3]);
                acc[3][0] = fmaf(a4.w, b4.x, acc[3][0]); acc[3][1] = fmaf(a4.w, b4.y, acc[3][1]);
                acc[3][2] = fmaf(a4.w, b4.z, acc[3][2]); acc[3][3] = fmaf(a4.w, b4.w, acc[3][3]);
            }
            __syncthreads();
        }
        float* Gb = G + (size_t)b * 4096;
#pragma unroll
        for (int i = 0; i < 4; i++)
#pragma unroll
            for (int j = 0; j < 4; j++)
                atomicAdd(&Gb[(r0 + i) * 64 + c0 + j], acc[i][j]);
    }
    grid.sync();

    // ================= phase 2: attention (blocks 0..127) ================
    if (bid < 128) {
        const int quad = bid & 3;
        const int bh = bid >> 2;
        const int b = bh >> 3, h = bh & 7;
        const int d0g = quad * 16;

        // ---- loads ----
#pragma unroll
        for (int k = 0; k < 4; k++) {
            int idx = k * 1024 + t * 4;
            int r = idx >> 6, c = idx & 63;
            float4 v = *reinterpret_cast<const float4*>(G + (size_t)b * 4096 + idx);
            *reinterpret_cast<float4*>(&Gs[r][c]) = v;
            float4 w = *reinterpret_cast<const float4*>(Wq + (size_t)r * INNER + h * 64 + c);
            *reinterpret_cast<float4*>(&Ws[r][c]) = w;
        }
        {
            int c = t >> 2, dl = (t & 3) * 4;
            float4 v = *reinterpret_cast<const float4*>(Wk + (size_t)c * INNER + h * 64 + d0g + dl);
            *reinterpret_cast<float4*>(&WkQ[c][dl]) = v;
        }
        float4 wvr[4];
#pragma unroll
        for (int k = 0; k < 4; k++) {
            int idx = k * 1024 + t * 4;
            int r = idx >> 6;
            wvr[k] = *reinterpret_cast<const float4*>(Wv + (size_t)r * INNER + h * 64 + (idx & 63));
        }
        float4 wpr;
        {
            int dl = t >> 4, c2 = (t & 15) * 4;
            wpr = *reinterpret_cast<const float4*>(Wp + (size_t)(h * 64 + d0g + dl) * 64 + c2);
        }
        __syncthreads();

        // ---- Tq[c][e] = sum_k G[k][c] Wq[k][e]  (G symmetric) ----
        const int ti = t >> 4, tj = t & 15;
        {
            float acc[4][4] = {};
            for (int k2 = 0; k2 < 64; k2++) {
                const float4 a4 = *reinterpret_cast<const float4*>(&Gs[k2][ti * 4]);
                const float4 b4 = *reinterpret_cast<const float4*>(&Ws[k2][tj * 4]);
                float a[4] = {a4.x, a4.y, a4.z, a4.w}, bv[4] = {b4.x, b4.y, b4.z, b4.w};
#pragma unroll
                for (int i = 0; i < 4; i++)
#pragma unroll
                    for (int j = 0; j < 4; j++) acc[i][j] = fmaf(a[i], bv[j], acc[i][j]);
            }
#pragma unroll
            for (int i = 0; i < 4; i++) {
                float4 v; v.x = acc[i][0]; v.y = acc[i][1]; v.z = acc[i][2]; v.w = acc[i][3];
                *reinterpret_cast<float4*>(&Tq[ti * 4 + i][tj * 4]) = v;
            }
        }
        // ---- TkQ[c][dl] = sum_k G[k][c] Wk[k][d0g+dl]  -> Atn ----
        {
            const int c = t >> 2, dl0 = (t & 3) * 4;
            float tk[4] = {};
            for (int k = 0; k < 64; k++) {
                const float a = Gs[k][c];
                const float4 b4 = *reinterpret_cast<const float4*>(&WkQ[k][dl0]);
                tk[0] = fmaf(a, b4.x, tk[0]); tk[1] = fmaf(a, b4.y, tk[1]);
                tk[2] = fmaf(a, b4.z, tk[2]); tk[3] = fmaf(a, b4.w, tk[3]);
            }
            float4 v; v.x = tk[0]; v.y = tk[1]; v.z = tk[2]; v.w = tk[3];
            *reinterpret_cast<float4*>(&Atn[c][dl0]) = v;
        }
        __syncthreads();

        // ---- qn: e = t>>2, 4 lanes each ----
        {
            const int e = t >> 2, sub = t & 3;
            float s = 0.f;
            for (int c = sub * 16; c < sub * 16 + 16; c++) s += Ws[c][e] * Tq[c][e];
            s += __shfl_xor(s, 1, 64);
            s += __shfl_xor(s, 2, 64);
            if (sub == 0) qn[e] = fmaxf(sqrtf(s), 1e-12f);
        }
        // ---- kn (t<64): dl = t>>2 ----
        if (t < 64) {
            const int dl = t >> 2, sub = t & 3;
            float s = 0.f;
            for (int c = sub * 16; c < sub * 16 + 16; c++) s += WkQ[c][dl] * Atn[c][dl];
            s += __shfl_xor(s, 1, 64);
            s += __shfl_xor(s, 2, 64);
            if (sub == 0) kn[dl] = fmaxf(sqrtf(s), 1e-12f);
        }
        // ---- S[d][e] = sum_c Wk[c][d0g+d] Tq[c][e]  (regs) ----
        const int d = t >> 4, e0 = (t & 15) * 4;
        float s4[4] = {};
        for (int c = 0; c < 64; c++) {
            const float a = WkQ[c][d];
            const float4 b4 = *reinterpret_cast<const float4*>(&Tq[c][e0]);
            s4[0] = fmaf(a, b4.x, s4[0]); s4[1] = fmaf(a, b4.y, s4[1]);
            s4[2] = fmaf(a, b4.z, s4[2]); s4[3] = fmaf(a, b4.w, s4[3]);
        }
        __syncthreads();

        // ---- softmax over e ----
        const float resc = rescale[h];
        float p[4];
        {
            const float ki = resc / kn[d];
            float m = -3.402823466e+38f;
#pragma unroll
            for (int j = 0; j < 4; j++) {
                p[j] = s4[j] * ki / qn[e0 + j];
                m = fmaxf(m, p[j]);
            }
            for (int o = 1; o < 16; o <<= 1) m = fmaxf(m, __shfl_xor(m, o, 64));
            float ssum = 0.f;
#pragma unroll
            for (int j = 0; j < 4; j++) { p[j] = expf(p[j] - m); ssum += p[j]; }
            for (int o = 1; o < 16; o <<= 1) ssum += __shfl_xor(ssum, o, 64);
            const float inv = 1.f / ssum;
#pragma unroll
            for (int j = 0; j < 4; j++) p[j] *= inv;
        }
        // write attn output + stash attnT into Atn
        {
            float4 v; v.x = p[0]; v.y = p[1]; v.z = p[2]; v.w = p[3];
            *reinterpret_cast<float4*>(attn_out + (size_t)bh * 4096 + (size_t)(d0g + d) * 64 + e0) = v;
#pragma unroll
            for (int j = 0; j < 4; j++) Atn[e0 + j][d] = p[j];
        }
        // Ws <- Wv ; Tq rows 16..31 <- Wp quarter
#pragma unroll
        for (int k = 0; k < 4; k++) {
            int idx = k * 1024 + t * 4;
            int r = idx >> 6, c = idx & 63;
            *reinterpret_cast<float4*>(&Ws[r][c]) = wvr[k];
        }
        {
            int dl = t >> 4, c2 = (t & 15) * 4;
            *reinterpret_cast<float4*>(&Tq[16 + dl][c2]) = wpr;
        }
        __syncthreads();

        // ---- WveffT[dl][c] = sum_e Wv[c][e] attnT[e][dl] -> Tq rows 0..15 ----
        {
            const int c = t >> 2, dl0 = (t & 3) * 4;
            float wv4[4] = {};
            for (int e = 0; e < 64; e++) {
                const float a = Ws[c][e];
                const float4 b4 = *reinterpret_cast<const float4*>(&Atn[e][dl0]);
                wv4[0] = fmaf(a, b4.x, wv4[0]); wv4[1] = fmaf(a, b4.y, wv4[1]);
                wv4[2] = fmaf(a, b4.z, wv4[2]); wv4[3] = fmaf(a, b4.w, wv4[3]);
            }
#pragma unroll
            for (int j = 0; j < 4; j++) Tq[dl0 + j][c] = wv4[j];
        }
        __syncthreads();

        // ---- M[c][c2] += sum_dl WveffT[dl][c] Wp[dl][c2] ----
        {
            float acc[4][4] = {};
#pragma unroll
            for (int dl = 0; dl < 16; dl++) {
                const float4 a4 = *reinterpret_cast<const float4*>(&Tq[dl][ti * 4]);
                const float4 b4 = *reinterpret_cast<const float4*>(&Tq[16 + dl][tj * 4]);
                float a[4] = {a4.x, a4.y, a4.z, a4.w}, bv[4] = {b4.x, b4.y, b4.z, b4.w};
#pragma unroll
                for (int i = 0; i < 4; i++)
#pragma unroll
                    for (int j = 0; j < 4; j++) acc[i][j] = fmaf(a[i], bv[j], acc[i][j]);
            }
            float* Mb = Mg + (size_t)b * 4096;
#pragma unroll
            for (int i = 0; i < 4; i++)
#pragma unroll
                for (int j = 0; j < 4; j++)
                    atomicAdd(&Mb[(ti * 4 + i) * 64 + tj * 4 + j], acc[i][j]);
        }
    }
    grid.sync();

    // ================= phase 3: out = M^T X + bp =========================
    {
        const int b = bid >> 6, s2 = bid & 63;
        const int ti = t >> 4, tj = t & 15;
        for (int k = 0; k < 16; k++) { int f = k * 256 + t; Ws[f >> 6][f & 63] = Mg[(size_t)b * 4096 + f]; }
        float bpv[4];
#pragma unroll
        for (int i = 0; i < 4; i++) bpv[i] = bp[ti * 4 + i];
        const float* xb = x + (size_t)b * CC * NN;
        float* ob = out + (size_t)b * CC * NN;
#pragma unroll
        for (int ss = 0; ss < 4; ++ss) {
            const int n0 = (s2 * 4 + ss) * 64;
            __syncthreads();
#pragma unroll
            for (int k = 0; k < 4; k++) {
                int f = k * 256 + t; int c = f >> 4, j4 = f & 15;
                float4 v = *reinterpret_cast<const float4*>(xb + (size_t)c * NN + n0 + j4 * 4);
                Gs[c][j4 * 4 + 0] = v.x; Gs[c][j4 * 4 + 1] = v.y;
                Gs[c][j4 * 4 + 2] = v.z; Gs[c][j4 * 4 + 3] = v.w;
            }
            __syncthreads();
            float acc[4][4];
#pragma unroll
            for (int i = 0; i < 4; i++)
#pragma unroll
                for (int j = 0; j < 4; j++) acc[i][j] = bpv[i];
            for (int c = 0; c < 64; c++) {
                const float4 m4 = *reinterpret_cast<const float4*>(&Ws[c][ti * 4]);
                const float4 x4 = *reinterpret_cast<const float4*>(&Gs[c][tj * 4]);
                float m[4] = {m4.x, m4.y, m4.z, m4.w}, xv[4] = {x4.x, x4.y, x4.z, x4.w};
#pragma unroll
                for (int i = 0; i < 4; i++)
#pragma unroll
                    for (int j = 0; j < 4; j++) acc[i][j] = fmaf(m[i], xv[j], acc[i][j]);
            }
#pragma unroll
            for (int i = 0; i < 4; i++) {
                float4 v; v.x = acc[i][0]; v.y = acc[i][1]; v.z = acc[i][2]; v.w = acc[i][3];
                *reinterpret_cast<float4*>(ob + (size_t)(ti * 4 + i) * NN + n0 + tj * 4) = v;
            }
        }
    }
}

extern "C" void kernel_launch(void* const* d_in, const int* in_sizes, int n_in,
                              void* d_out, int out_size, void* d_ws, size_t ws_size,
                              hipStream_t stream) {
    const float* x  = (const float*)d_in[0];
    const float* Wq = (const float*)d_in[1];
    const float* Wk = (const float*)d_in[2];
    const float* Wv = (const float*)d_in[3];
    const float* Wp = (const float*)d_in[4];
    const float* bp = (const float*)d_in[5];
    const float* rescale = (const float*)d_in[6];
    float* out = (float*)d_out;
    float* attn_out = out + (size_t)BB * CC * NN;
    float* ws = (float*)d_ws;

    float* G  = ws;                          // [BB][4096]
    float* Mg = G + (size_t)BB * 4096;       // [BB][4096]

    hipMemsetAsync(G, 0, (size_t)BB * 4096 * 2 * sizeof(float), stream);
    void* args[] = { (void*)&x, (void*)&Wq, (void*)&Wk, (void*)&Wv, (void*)&Wp,
                     (void*)&bp, (void*)&rescale, (void*)&attn_out,
                     (void*)&G, (void*)&Mg, (void*)&out };
    hipLaunchCooperativeKernel((void*)k_fused, dim3(256), dim3(256), args, 0, stream);
}

// Round 8
// 143.004 us; speedup vs baseline: 1.4952x; 1.4952x over previous
//
#include <hip/hip_runtime.h>
#include <math.h>

#define BB 4
#define CC 64
#define NN 16384   // 128*128
#define HEADS 8
#define INNER 512

// ---------------- Kernel 1: partial Gram G_b = X_b X_b^T ----------------
// grid (nslice, BB), 256 threads, 4 blocks/CU at nslice=256. Each wave owns a
// 16-row strip of the 64x64 output. Blocks with s==0 also zero Mg[b].
__global__ __launch_bounds__(256) void k_gram(const float* __restrict__ x,
                                              float* __restrict__ part,
                                              float* __restrict__ Mg,
                                              int nslice) {
    const int s = blockIdx.x, b = blockIdx.y;
    const int t = threadIdx.x;
    if (s == 0) {  // zero M accumulator for this batch (used by k_attn later)
        float* Mb = Mg + (size_t)b * 4096;
#pragma unroll
        for (int k = 0; k < 16; k++) Mb[k * 256 + t] = 0.f;
    }
    const int g = t >> 6, lane = t & 63;
    const int rg = lane >> 4;
    const int r0 = g * 16 + rg * 4;        // output row block (c-dim)
    const int c0 = (lane & 15) * 4;        // output col block (c-dim)
    __shared__ float xs[64][68];           // [n][c], 272B rows (16B aligned)
    float acc[4][4];
#pragma unroll
    for (int i = 0; i < 4; i++)
#pragma unroll
        for (int j = 0; j < 4; j++) acc[i][j] = 0.f;

    const float* xb = x + (size_t)b * CC * NN;
    const int cols = NN / nslice;
    const int ntiles = cols >> 6;
    const int nbase = s * cols;
    for (int tile = 0; tile < ntiles; ++tile) {
        const int n0 = nbase + tile * 64;
#pragma unroll
        for (int k = 0; k < 4; k++) {
            int f = k * 256 + t;
            int c = f >> 4, j4 = f & 15;
            const float4 v = *reinterpret_cast<const float4*>(xb + (size_t)c * NN + n0 + j4 * 4);
            xs[j4 * 4 + 0][c] = v.x; xs[j4 * 4 + 1][c] = v.y;
            xs[j4 * 4 + 2][c] = v.z; xs[j4 * 4 + 3][c] = v.w;
        }
        __syncthreads();
#pragma unroll 8
        for (int n = 0; n < 64; ++n) {
            const float4 a4 = *reinterpret_cast<const float4*>(&xs[n][r0]);
            const float4 b4 = *reinterpret_cast<const float4*>(&xs[n][c0]);
            acc[0][0] = fmaf(a4.x, b4.x, acc[0][0]); acc[0][1] = fmaf(a4.x, b4.y, acc[0][1]);
            acc[0][2] = fmaf(a4.x, b4.z, acc[0][2]); acc[0][3] = fmaf(a4.x, b4.w, acc[0][3]);
            acc[1][0] = fmaf(a4.y, b4.x, acc[1][0]); acc[1][1] = fmaf(a4.y, b4.y, acc[1][1]);
            acc[1][2] = fmaf(a4.y, b4.z, acc[1][2]); acc[1][3] = fmaf(a4.y, b4.w, acc[1][3]);
            acc[2][0] = fmaf(a4.z, b4.x, acc[2][0]); acc[2][1] = fmaf(a4.z, b4.y, acc[2][1]);
            acc[2][2] = fmaf(a4.z, b4.z, acc[2][2]); acc[2][3] = fmaf(a4.z, b4.w, acc[2][3]);
            acc[3][0] = fmaf(a4.w, b4.x, acc[3][0]); acc[3][1] = fmaf(a4.w, b4.y, acc[3][1]);
            acc[3][2] = fmaf(a4.w, b4.z, acc[3][2]); acc[3][3] = fmaf(a4.w, b4.w, acc[3][3]);
        }
        __syncthreads();
    }
    float* p = part + (size_t)(b * nslice + s) * 4096;
#pragma unroll
    for (int i = 0; i < 4; i++) {
        float4 v; v.x = acc[i][0]; v.y = acc[i][1]; v.z = acc[i][2]; v.w = acc[i][3];
        *reinterpret_cast<float4*>(p + (r0 + i) * 64 + c0) = v;
    }
}

// ---------------- Kernel 2a: reduce Gram partials ----------------
__global__ __launch_bounds__(256) void k_redG(const float* __restrict__ part,
                                              float* __restrict__ G,
                                              int nslice) {
    const int b = blockIdx.y;
    const int idx = blockIdx.x * 256 + threadIdx.x;
    const float* p = part + (size_t)b * nslice * 4096 + idx;
    float s0 = 0.f, s1 = 0.f, s2 = 0.f, s3 = 0.f;
    for (int s = 0; s < nslice; s += 4) {
        s0 += p[(size_t)s * 4096];
        s1 += p[(size_t)(s + 1) * 4096];
        s2 += p[(size_t)(s + 2) * 4096];
        s3 += p[(size_t)(s + 3) * 4096];
    }
    G[(size_t)b * 4096 + idx] = (s0 + s1) + (s2 + s3);
}

// ---------------- Kernel 2b: per-(b,h,dquad) attention + M (atomic) ---------
// grid 128: quad = blockIdx.x & 3 owns d in [quad*16, quad*16+16).
__global__ __launch_bounds__(256) void k_attn(const float* __restrict__ G,
                                              const float* __restrict__ Wq,
                                              const float* __restrict__ Wk,
                                              const float* __restrict__ Wv,
                                              const float* __restrict__ Wp,
                                              const float* __restrict__ rescale,
                                              float* __restrict__ attn_out,
                                              float* __restrict__ Mg) {
    const int quad = blockIdx.x & 3;
    const int bh = blockIdx.x >> 2;
    const int b = bh >> 3, h = bh & 7;
    const int d0g = quad * 16;
    const int t = threadIdx.x;

    __shared__ float Gs[64][68];   // G (symmetric)
    __shared__ float Tq[64][68];   // Tq; later rows0-15 = WveffT, rows16-31 = Wp
    __shared__ float Ws[64][68];   // Wq, then Wv
    __shared__ float WkQ[64][20];  // Wk[:, d0g:d0g+16]
    __shared__ float Atn[64][20];  // TkQ, then attnT
    __shared__ float qn[64], kn[16];

    // ---- loads ----
#pragma unroll
    for (int k = 0; k < 4; k++) {
        int idx = k * 1024 + t * 4;
        int r = idx >> 6, c = idx & 63;
        float4 v = *reinterpret_cast<const float4*>(G + (size_t)b * 4096 + idx);
        *reinterpret_cast<float4*>(&Gs[r][c]) = v;
        float4 w = *reinterpret_cast<const float4*>(Wq + (size_t)r * INNER + h * 64 + c);
        *reinterpret_cast<float4*>(&Ws[r][c]) = w;
    }
    {
        int c = t >> 2, dl = (t & 3) * 4;
        float4 v = *reinterpret_cast<const float4*>(Wk + (size_t)c * INNER + h * 64 + d0g + dl);
        *reinterpret_cast<float4*>(&WkQ[c][dl]) = v;
    }
    float4 wvr[4];
#pragma unroll
    for (int k = 0; k < 4; k++) {
        int idx = k * 1024 + t * 4;
        int r = idx >> 6;
        wvr[k] = *reinterpret_cast<const float4*>(Wv + (size_t)r * INNER + h * 64 + (idx & 63));
    }
    float4 wpr;
    {
        int dl = t >> 4, c2 = (t & 15) * 4;
        wpr = *reinterpret_cast<const float4*>(Wp + (size_t)(h * 64 + d0g + dl) * 64 + c2);
    }
    __syncthreads();

    // ---- Tq[c][e] = sum_k G[k][c] Wq[k][e]  (G symmetric) ----
    const int ti = t >> 4, tj = t & 15;
    {
        float acc[4][4] = {};
        for (int k2 = 0; k2 < 64; k2++) {
            const float4 a4 = *reinterpret_cast<const float4*>(&Gs[k2][ti * 4]);
            const float4 b4 = *reinterpret_cast<const float4*>(&Ws[k2][tj * 4]);
            float a[4] = {a4.x, a4.y, a4.z, a4.w}, bv[4] = {b4.x, b4.y, b4.z, b4.w};
#pragma unroll
            for (int i = 0; i < 4; i++)
#pragma unroll
                for (int j = 0; j < 4; j++) acc[i][j] = fmaf(a[i], bv[j], acc[i][j]);
        }
#pragma unroll
        for (int i = 0; i < 4; i++) {
            float4 v; v.x = acc[i][0]; v.y = acc[i][1]; v.z = acc[i][2]; v.w = acc[i][3];
            *reinterpret_cast<float4*>(&Tq[ti * 4 + i][tj * 4]) = v;
        }
    }
    // ---- TkQ[c][dl] = sum_k G[k][c] Wk[k][d0g+dl]  -> Atn ----
    {
        const int c = t >> 2, dl0 = (t & 3) * 4;
        float tk[4] = {};
        for (int k = 0; k < 64; k++) {
            const float a = Gs[k][c];
            const float4 b4 = *reinterpret_cast<const float4*>(&WkQ[k][dl0]);
            tk[0] = fmaf(a, b4.x, tk[0]); tk[1] = fmaf(a, b4.y, tk[1]);
            tk[2] = fmaf(a, b4.z, tk[2]); tk[3] = fmaf(a, b4.w, tk[3]);
        }
        float4 v; v.x = tk[0]; v.y = tk[1]; v.z = tk[2]; v.w = tk[3];
        *reinterpret_cast<float4*>(&Atn[c][dl0]) = v;
    }
    __syncthreads();

    // ---- qn: e = t>>2, 4 lanes each ----
    {
        const int e = t >> 2, sub = t & 3;
        float s = 0.f;
        for (int c = sub * 16; c < sub * 16 + 16; c++) s += Ws[c][e] * Tq[c][e];
        s += __shfl_xor(s, 1, 64);
        s += __shfl_xor(s, 2, 64);
        if (sub == 0) qn[e] = fmaxf(sqrtf(s), 1e-12f);
    }
    // ---- kn (t<64): dl = t>>2 ----
    if (t < 64) {
        const int dl = t >> 2, sub = t & 3;
        float s = 0.f;
        for (int c = sub * 16; c < sub * 16 + 16; c++) s += WkQ[c][dl] * Atn[c][dl];
        s += __shfl_xor(s, 1, 64);
        s += __shfl_xor(s, 2, 64);
        if (sub == 0) kn[dl] = fmaxf(sqrtf(s), 1e-12f);
    }
    // ---- S[d][e] = sum_c Wk[c][d0g+d] Tq[c][e]  (regs) ----
    const int d = t >> 4, e0 = (t & 15) * 4;
    float s4[4] = {};
    for (int c = 0; c < 64; c++) {
        const float a = WkQ[c][d];
        const float4 b4 = *reinterpret_cast<const float4*>(&Tq[c][e0]);
        s4[0] = fmaf(a, b4.x, s4[0]); s4[1] = fmaf(a, b4.y, s4[1]);
        s4[2] = fmaf(a, b4.z, s4[2]); s4[3] = fmaf(a, b4.w, s4[3]);
    }
    __syncthreads();

    // ---- softmax over e ----
    const float resc = rescale[h];
    float p[4];
    {
        const float ki = resc / kn[d];
        float m = -3.402823466e+38f;
#pragma unroll
        for (int j = 0; j < 4; j++) {
            p[j] = s4[j] * ki / qn[e0 + j];
            m = fmaxf(m, p[j]);
        }
        for (int o = 1; o < 16; o <<= 1) m = fmaxf(m, __shfl_xor(m, o, 64));
        float ssum = 0.f;
#pragma unroll
        for (int j = 0; j < 4; j++) { p[j] = expf(p[j] - m); ssum += p[j]; }
        for (int o = 1; o < 16; o <<= 1) ssum += __shfl_xor(ssum, o, 64);
        const float inv = 1.f / ssum;
#pragma unroll
        for (int j = 0; j < 4; j++) p[j] *= inv;
    }
    // write attn output + stash attnT into Atn (overwrites TkQ)
    {
        float4 v; v.x = p[0]; v.y = p[1]; v.z = p[2]; v.w = p[3];
        *reinterpret_cast<float4*>(attn_out + (size_t)bh * 4096 + (size_t)(d0g + d) * 64 + e0) = v;
#pragma unroll
        for (int j = 0; j < 4; j++) Atn[e0 + j][d] = p[j];
    }
    // Ws <- Wv ; Tq rows 16..31 <- Wp quarter
#pragma unroll
    for (int k = 0; k < 4; k++) {
        int idx = k * 1024 + t * 4;
        int r = idx >> 6, c = idx & 63;
        *reinterpret_cast<float4*>(&Ws[r][c]) = wvr[k];
    }
    {
        int dl = t >> 4, c2 = (t & 15) * 4;
        *reinterpret_cast<float4*>(&Tq[16 + dl][c2]) = wpr;
    }
    __syncthreads();

    // ---- WveffT[dl][c] = sum_e Wv[c][e] attnT[e][dl]  -> Tq rows 0..15 ----
    {
        const int c = t >> 2, dl0 = (t & 3) * 4;
        float wv4[4] = {};
        for (int e = 0; e < 64; e++) {
            const float a = Ws[c][e];
            const float4 b4 = *reinterpret_cast<const float4*>(&Atn[e][dl0]);
            wv4[0] = fmaf(a, b4.x, wv4[0]); wv4[1] = fmaf(a, b4.y, wv4[1]);
            wv4[2] = fmaf(a, b4.z, wv4[2]); wv4[3] = fmaf(a, b4.w, wv4[3]);
        }
#pragma unroll
        for (int j = 0; j < 4; j++) Tq[dl0 + j][c] = wv4[j];
    }
    __syncthreads();

    // ---- M[c][c2] += sum_dl WveffT[dl][c] Wp[dl][c2] ----
    {
        float acc[4][4] = {};
#pragma unroll
        for (int dl = 0; dl < 16; dl++) {
            const float4 a4 = *reinterpret_cast<const float4*>(&Tq[dl][ti * 4]);
            const float4 b4 = *reinterpret_cast<const float4*>(&Tq[16 + dl][tj * 4]);
            float a[4] = {a4.x, a4.y, a4.z, a4.w}, bv[4] = {b4.x, b4.y, b4.z, b4.w};
#pragma unroll
            for (int i = 0; i < 4; i++)
#pragma unroll
                for (int j = 0; j < 4; j++) acc[i][j] = fmaf(a[i], bv[j], acc[i][j]);
        }
        float* Mb = Mg + (size_t)b * 4096;
#pragma unroll
        for (int i = 0; i < 4; i++)
#pragma unroll
            for (int j = 0; j < 4; j++)
                atomicAdd(&Mb[(ti * 4 + i) * 64 + tj * 4 + j], acc[i][j]);
    }
}

// ---------------- Kernel 3: out = M^T X + bp ----------------
__global__ __launch_bounds__(256) void k_out(const float* __restrict__ x,
                                             const float* __restrict__ Mg,
                                             const float* __restrict__ bp,
                                             float* __restrict__ out) {
    const int sn = blockIdx.x, b = blockIdx.y;
    const int t = threadIdx.x, ti = t >> 4, tj = t & 15;
    __shared__ float Ms[64][68], xs[64][68];
    for (int k = 0; k < 16; k++) { int f = k * 256 + t; Ms[f >> 6][f & 63] = Mg[(size_t)b * 4096 + f]; }
    const int n0 = sn * 64;
    const float* xb = x + (size_t)b * CC * NN;
#pragma unroll
    for (int k = 0; k < 4; k++) {
        int f = k * 256 + t; int c = f >> 4, j4 = f & 15;
        float4 v = *reinterpret_cast<const float4*>(xb + (size_t)c * NN + n0 + j4 * 4);
        xs[c][j4 * 4 + 0] = v.x; xs[c][j4 * 4 + 1] = v.y;
        xs[c][j4 * 4 + 2] = v.z; xs[c][j4 * 4 + 3] = v.w;
    }
    __syncthreads();
    float acc[4][4];
#pragma unroll
    for (int i = 0; i < 4; i++) {
        const float bv = bp[ti * 4 + i];
#pragma unroll
        for (int j = 0; j < 4; j++) acc[i][j] = bv;
    }
    for (int c = 0; c < 64; c++) {
        const float4 m4 = *reinterpret_cast<const float4*>(&Ms[c][ti * 4]);
        const float4 x4 = *reinterpret_cast<const float4*>(&xs[c][tj * 4]);
        float m[4] = {m4.x, m4.y, m4.z, m4.w}, xv[4] = {x4.x, x4.y, x4.z, x4.w};
#pragma unroll
        for (int i = 0; i < 4; i++)
#pragma unroll
            for (int j = 0; j < 4; j++) acc[i][j] = fmaf(m[i], xv[j], acc[i][j]);
    }
    float* ob = out + (size_t)b * CC * NN;
#pragma unroll
    for (int i = 0; i < 4; i++) {
        float4 v; v.x = acc[i][0]; v.y = acc[i][1]; v.z = acc[i][2]; v.w = acc[i][3];
        *reinterpret_cast<float4*>(ob + (size_t)(ti * 4 + i) * NN + n0 + tj * 4) = v;
    }
}

extern "C" void kernel_launch(void* const* d_in, const int* in_sizes, int n_in,
                              void* d_out, int out_size, void* d_ws, size_t ws_size,
                              hipStream_t stream) {
    const float* x  = (const float*)d_in[0];
    const float* Wq = (const float*)d_in[1];
    const float* Wk = (const float*)d_in[2];
    const float* Wv = (const float*)d_in[3];
    const float* Wp = (const float*)d_in[4];
    const float* bp = (const float*)d_in[5];
    const float* rescale = (const float*)d_in[6];
    float* out = (float*)d_out;
    float* attn_out = out + (size_t)BB * CC * NN;
    float* ws = (float*)d_ws;

    // pick the largest slice count whose workspace fits ws_size
    const size_t fixed_floats = (size_t)BB * 4096     // G
                              + (size_t)BB * 4096;    // Mg
    int nslice = 256;
    while (nslice > 4 &&
           ((size_t)BB * nslice * 4096 + fixed_floats) * sizeof(float) > ws_size)
        nslice >>= 1;

    float* part = ws;
    float* G    = part + (size_t)BB * nslice * 4096;
    float* Mg   = G + (size_t)BB * 4096;

    hipLaunchKernelGGL(k_gram, dim3(nslice, BB),     dim3(256), 0, stream, x, part, Mg, nslice);
    hipLaunchKernelGGL(k_redG, dim3(16, BB),         dim3(256), 0, stream, part, G, nslice);
    hipLaunchKernelGGL(k_attn, dim3(BB * HEADS * 4), dim3(256), 0, stream, G, Wq, Wk, Wv, Wp, rescale, attn_out, Mg);
    hipLaunchKernelGGL(k_out,  dim3(NN / 64, BB),    dim3(256), 0, stream, x, Mg, bp, out);
}